// Round 4
// baseline (150.835 us; speedup 1.0000x reference)
//
#include <hip/hip_runtime.h>
#include <stdint.h>

// Problem: LTCCell  B=256, I=512, H=512. ALL tensors float32, output float32.
// R5 (best): 2048 blocks, TB=8, 8 waves/SIMD, accum 45us, VALUBusy 61%.
// R6 (rcp-share) FAILED 50us; R7 (dist-2 prefetch) NEUTRAL, FETCH x2;
// R8 (store-partials, no memset) NEUTRAL total -> launches aren't the cost.
//   R8 counters exposed harness ws-poison: fillBufferAligned 48.6us/iter
//   (256MiB @5.5TB/s) INSIDE the timed window. Budget: 123 = 48.6(poison,
//   fixed) + 45(accum) + ~5(memset+epi) + ~20(gaps, fixed).
// R9 THEORY: accum model refit: trans ~12cy, plain 2cy -> issue floor
//   28.6us; measured 45us @61% busy. Missing 39% = L2 BW: params read
//   512KB/block x 2048 = 1.0GB / 45us = 23 TB/s = 67% of L2 ceiling.
//   Fix: TB 8->16 (param element reused 16x, L2 traffic halved to 512MB
//   ~ 15us demand, under issue floor). Keep 2048 blocks: CHUNK 32->16,
//   NSPL 32->64. Regs: 2x 8-chain groups -> est ~48-56 VGPR (<64 cap).
//   Predict accum 34-38us, VALUBusy 75-85%, total ~112-116us.
constexpr int NB = 256;
constexpr int NI = 512;
constexpr int NH = 512;

constexpr int TB    = 16;   // batches register-blocked per lane
constexpr int NT    = 16;   // batch tiles: 256/16
constexpr int CHUNK = 16;   // reduction rows per block
constexpr int NSPL  = 64;   // splits: 32 sensory chunks + 32 inter chunks
constexpr int HBLK  = 256;  // h columns per block (== blockDim.x)

__device__ __forceinline__ float fast_exp2(float x) {
#if __has_builtin(__builtin_amdgcn_exp2f)
    return __builtin_amdgcn_exp2f(x);
#else
    return exp2f(x);
#endif
}
__device__ __forceinline__ float fast_rcp(float x) {
#if __has_builtin(__builtin_amdgcn_rcpf)
    return __builtin_amdgcn_rcpf(x);
#else
    return 1.0f / x;
#endif
}

// Each block = (split sigma, batch tile, h half). 2048 blocks x 256 thr =
// 8 blocks/CU = 8 waves/SIMD (exact machine fit). Lane <-> h column, 16
// batches register-blocked per lane (2 groups of 8 independent chains).
// Partials combined via f32 atomics (proven path; memset is ~3us).
__global__ __launch_bounds__(256, 8) void ltc_accum(
    const float* __restrict__ inputs,   // NB x NI
    const float* __restrict__ state,    // NB x NH
    const float* __restrict__ smu, const float* __restrict__ ssg,
    const float* __restrict__ sW,  const float* __restrict__ ser,
    const float* __restrict__ imu, const float* __restrict__ isg,
    const float* __restrict__ iW,  const float* __restrict__ ier,
    float* __restrict__ wsNum, float* __restrict__ wsDen)
{
    __shared__ float xs[CHUNK][TB];   // x/state chunk, [row][batch]

    const int bi    = blockIdx.x;
    const int sigma = bi & (NSPL - 1);          // 64 splits
    const int btile = (bi >> 6) & (NT - 1);     // 16 batch tiles
    const int hhalf = bi >> 10;                 // 2 h halves
    const int b0 = btile * TB;
    const int h  = hhalf * HBLK + threadIdx.x;

    const bool sens = sigma < 32;
    const int  r0   = (sens ? sigma : sigma - 32) * CHUNK;

    // Side-selected pointers (block-uniform -> scalar select, no divergence).
    const float* __restrict__ src  = sens ? inputs : state;   // NB x 512
    const float* __restrict__ Pmu  = sens ? smu : imu;
    const float* __restrict__ Psg  = sens ? ssg : isg;
    const float* __restrict__ PW   = sens ? sW  : iW;
    const float* __restrict__ Per  = sens ? ser : ier;

    // Stage x/state chunk to LDS, [row][batch] layout. CHUNK*TB == 256.
    {
        const int ii = threadIdx.x >> 4, bb = threadIdx.x & (TB - 1);
        xs[ii][bb] = src[(b0 + bb) * 512 + r0 + ii];
    }
    __syncthreads();

    float num[TB], den[TB];
#pragma unroll
    for (int bb = 0; bb < TB; ++bb) { num[bb] = 0.f; den[bb] = 0.f; }

    const float LOG2E = 1.44269504088896340736f;

    // sigmoid((x-mu)*sig) = 1/(1+exp2(c - x*a)), a = sig*log2e, c = mu*a.
    // exp2 overflow -> inf -> rcp gives 0: correct saturation.
#pragma unroll 2
    for (int ii = 0; ii < CHUNK; ++ii) {
        const int p = (r0 + ii) * NH + h;          // coalesced across lanes
        const float mu = Pmu[p];
        const float a  = Psg[p] * LOG2E;
        const float W  = PW[p];
        const float We = W * Per[p];
        const float c  = mu * a;
#pragma unroll
        for (int g = 0; g < TB; g += 8) {
            float r[8];                            // 8 independent chains
#pragma unroll
            for (int j = 0; j < 8; ++j)
                r[j] = fast_rcp(1.0f + fast_exp2(c - xs[ii][g + j] * a));
#pragma unroll
            for (int j = 0; j < 8; ++j) {
                den[g + j] += W  * r[j];
                num[g + j] += We * r[j];
            }
        }
    }

#pragma unroll
    for (int bb = 0; bb < TB; ++bb) {
        unsafeAtomicAdd(&wsNum[(b0 + bb) * NH + h], num[bb]);  // global_atomic_add_f32
        unsafeAtomicAdd(&wsDen[(b0 + bb) * NH + h], den[bb]);
    }
}

// Epilogue: one thread per (b,h). Cheap relative to accumulation.
__global__ __launch_bounds__(256) void ltc_epilogue(
    const float* __restrict__ state,
    const float* __restrict__ vleak, const float* __restrict__ gleak,
    const float* __restrict__ cm,
    const float* __restrict__ wsNum, const float* __restrict__ wsDen,
    float* __restrict__ out)
{
    const int t = blockIdx.x * 256 + threadIdx.x;  // < NB*NH
    const int h = t & (NH - 1);
    const float st = state[t];
    const float gl = gleak[h];
    const float vl = vleak[h];
    const float c  = cm[h];
    const float wnum = wsNum[t];
    const float wden = wsDen[t];
    const float eps = 1e-8f;
    const float G = gl + wden;
    const float tau = c / (G + eps);
    const float numerator = c * st + gl * vl + wnum;
    const float denominator = c + G;
    const float v_inf = numerator / (denominator + eps);
    const float next = v_inf + (st - v_inf) * expf(-0.1f / (tau + eps));
    out[t] = tanhf(next);
}

extern "C" void kernel_launch(void* const* d_in, const int* in_sizes, int n_in,
                              void* d_out, int out_size, void* d_ws, size_t ws_size,
                              hipStream_t stream) {
    const float* inputs = (const float*)d_in[0];
    const float* state  = (const float*)d_in[1];
    const float* smu    = (const float*)d_in[2];
    const float* ssg    = (const float*)d_in[3];
    const float* sW     = (const float*)d_in[4];
    const float* ser    = (const float*)d_in[5];
    const float* imu    = (const float*)d_in[6];
    const float* isg    = (const float*)d_in[7];
    const float* iW     = (const float*)d_in[8];
    const float* ier    = (const float*)d_in[9];
    const float* vleak  = (const float*)d_in[10];
    const float* gleak  = (const float*)d_in[11];
    const float* cm     = (const float*)d_in[12];

    float* wsNum = (float*)d_ws;
    float* wsDen = wsNum + NB * NH;

    // ws is re-poisoned (0xAA) before every timed launch -> zero it ourselves.
    hipMemsetAsync(d_ws, 0, 2ull * NB * NH * sizeof(float), stream);

    ltc_accum<<<dim3(NSPL * NT * 2), dim3(256), 0, stream>>>(
        inputs, state, smu, ssg, sW, ser, imu, isg, iW, ier, wsNum, wsDen);
    ltc_epilogue<<<dim3(NB * NH / 256), dim3(256), 0, stream>>>(
        state, vleak, gleak, cm, wsNum, wsDen, (float*)d_out);
}

// Round 6
// 119.202 us; speedup vs baseline: 1.2654x; 1.2654x over previous
//
#include <hip/hip_runtime.h>
#include <stdint.h>

// Problem: LTCCell  B=256, I=512, H=512. ALL tensors float32, output float32.
// R5 (best): 2048 blocks, TB=8, CHUNK=32, NSPL=32, 8 waves/SIMD, accum 45us,
//     VALUBusy 61% (busy 27.5us vs ~28us issue floor -> 17.5us stall).
// R6 rcp-share FAILED (+5us); R7 manual dist-2 prefetch NEUTRAL (broke the
//     compiler's load batching, FETCH x2); R8 store-partials NEUTRAL (total
//     budget: poison 48.6us + gaps ~21us are harness-fixed); R9 TB=16
//     REGRESSED (+26us: same busy time, doubled stall; VGPR pinned at 32
//     despite 32 live accumulators + 64-deep atomic contention).
// R10: exact R5 body, ONE change: full unroll of the ii loop (was unroll 2).
//     Compiler sees all 128 param loads -> deep load clustering + batched
//     vmcnt (its own counted-vmcnt pipeline), without R7's manual rotation
//     that broke batching. Predict: if stall==load-latency scheduling,
//     accum 34-39us, VALUBusy 72-85%, VGPR 40-64. If neutral at ~45us/61%:
//     stall is structural trans-pipe -> declare roofline (~120us floor).
//     (R10 resubmit: previous round failed on container infra, not kernel.)
constexpr int NB = 256;
constexpr int NI = 512;
constexpr int NH = 512;

constexpr int TB    = 8;    // batches register-blocked per lane
constexpr int NT    = 32;   // batch tiles: 256/8
constexpr int CHUNK = 32;   // reduction rows per block
constexpr int NSPL  = 32;   // splits: 16 sensory chunks + 16 inter chunks
constexpr int HBLK  = 256;  // h columns per block (== blockDim.x)

__device__ __forceinline__ float fast_exp2(float x) {
#if __has_builtin(__builtin_amdgcn_exp2f)
    return __builtin_amdgcn_exp2f(x);
#else
    return exp2f(x);
#endif
}
__device__ __forceinline__ float fast_rcp(float x) {
#if __has_builtin(__builtin_amdgcn_rcpf)
    return __builtin_amdgcn_rcpf(x);
#else
    return 1.0f / x;
#endif
}

// Each block = (split sigma, batch tile, h half). 2048 blocks x 256 thr =
// 8 blocks/CU = 8 waves/SIMD (exact machine fit). Lane <-> h column, 8
// batches register-blocked per lane (r[8] ILP). Partials via f32 atomics.
__global__ __launch_bounds__(256, 8) void ltc_accum(
    const float* __restrict__ inputs,   // NB x NI
    const float* __restrict__ state,    // NB x NH
    const float* __restrict__ smu, const float* __restrict__ ssg,
    const float* __restrict__ sW,  const float* __restrict__ ser,
    const float* __restrict__ imu, const float* __restrict__ isg,
    const float* __restrict__ iW,  const float* __restrict__ ier,
    float* __restrict__ wsNum, float* __restrict__ wsDen)
{
    __shared__ float xs[CHUNK][TB];   // x/state chunk, [row][batch]

    const int bi    = blockIdx.x;
    const int sigma = bi & (NSPL - 1);          // 32 splits
    const int btile = (bi >> 5) & (NT - 1);     // 32 batch tiles
    const int hhalf = bi >> 10;                 // 2 h halves
    const int b0 = btile * TB;
    const int h  = hhalf * HBLK + threadIdx.x;

    const bool sens = sigma < 16;
    const int  r0   = (sens ? sigma : sigma - 16) * CHUNK;

    // Side-selected pointers (block-uniform -> scalar select, no divergence).
    const float* __restrict__ src  = sens ? inputs : state;   // NB x 512
    const float* __restrict__ Pmu  = sens ? smu : imu;
    const float* __restrict__ Psg  = sens ? ssg : isg;
    const float* __restrict__ PW   = sens ? sW  : iW;
    const float* __restrict__ Per  = sens ? ser : ier;

    // Stage x/state chunk to LDS, [row][batch] layout. CHUNK*TB == 256.
    {
        const int ii = threadIdx.x >> 3, bb = threadIdx.x & (TB - 1);
        xs[ii][bb] = src[(b0 + bb) * 512 + r0 + ii];
    }
    __syncthreads();

    float num[TB], den[TB];
#pragma unroll
    for (int bb = 0; bb < TB; ++bb) { num[bb] = 0.f; den[bb] = 0.f; }

    const float LOG2E = 1.44269504088896340736f;

    // sigmoid((x-mu)*sig) = 1/(1+exp2(c - x*a)), a = sig*log2e, c = mu*a.
    // exp2 overflow -> inf -> rcp gives 0: correct saturation.
    // FULL unroll: compiler sees all 128 param loads -> deep load batching.
#pragma unroll
    for (int ii = 0; ii < CHUNK; ++ii) {
        const int p = (r0 + ii) * NH + h;          // coalesced across lanes
        const float mu = Pmu[p];
        const float a  = Psg[p] * LOG2E;
        const float W  = PW[p];
        const float We = W * Per[p];
        const float c  = mu * a;
        float r[TB];                               // 8 independent chains
#pragma unroll
        for (int bb = 0; bb < TB; ++bb)
            r[bb] = fast_rcp(1.0f + fast_exp2(c - xs[ii][bb] * a));
#pragma unroll
        for (int bb = 0; bb < TB; ++bb) {
            den[bb] += W  * r[bb];
            num[bb] += We * r[bb];
        }
    }

#pragma unroll
    for (int bb = 0; bb < TB; ++bb) {
        unsafeAtomicAdd(&wsNum[(b0 + bb) * NH + h], num[bb]);  // global_atomic_add_f32
        unsafeAtomicAdd(&wsDen[(b0 + bb) * NH + h], den[bb]);
    }
}

// Epilogue: one thread per (b,h). Cheap relative to accumulation.
__global__ __launch_bounds__(256) void ltc_epilogue(
    const float* __restrict__ state,
    const float* __restrict__ vleak, const float* __restrict__ gleak,
    const float* __restrict__ cm,
    const float* __restrict__ wsNum, const float* __restrict__ wsDen,
    float* __restrict__ out)
{
    const int t = blockIdx.x * 256 + threadIdx.x;  // < NB*NH
    const int h = t & (NH - 1);
    const float st = state[t];
    const float gl = gleak[h];
    const float vl = vleak[h];
    const float c  = cm[h];
    const float wnum = wsNum[t];
    const float wden = wsDen[t];
    const float eps = 1e-8f;
    const float G = gl + wden;
    const float tau = c / (G + eps);
    const float numerator = c * st + gl * vl + wnum;
    const float denominator = c + G;
    const float v_inf = numerator / (denominator + eps);
    const float next = v_inf + (st - v_inf) * expf(-0.1f / (tau + eps));
    out[t] = tanhf(next);
}

extern "C" void kernel_launch(void* const* d_in, const int* in_sizes, int n_in,
                              void* d_out, int out_size, void* d_ws, size_t ws_size,
                              hipStream_t stream) {
    const float* inputs = (const float*)d_in[0];
    const float* state  = (const float*)d_in[1];
    const float* smu    = (const float*)d_in[2];
    const float* ssg    = (const float*)d_in[3];
    const float* sW     = (const float*)d_in[4];
    const float* ser    = (const float*)d_in[5];
    const float* imu    = (const float*)d_in[6];
    const float* isg    = (const float*)d_in[7];
    const float* iW     = (const float*)d_in[8];
    const float* ier    = (const float*)d_in[9];
    const float* vleak  = (const float*)d_in[10];
    const float* gleak  = (const float*)d_in[11];
    const float* cm     = (const float*)d_in[12];

    float* wsNum = (float*)d_ws;
    float* wsDen = wsNum + NB * NH;

    // ws is re-poisoned (0xAA) before every timed launch -> zero it ourselves.
    hipMemsetAsync(d_ws, 0, 2ull * NB * NH * sizeof(float), stream);

    ltc_accum<<<dim3(NSPL * NT * 2), dim3(256), 0, stream>>>(
        inputs, state, smu, ssg, sW, ser, imu, isg, iW, ier, wsNum, wsDen);
    ltc_epilogue<<<dim3(NB * NH / 256), dim3(256), 0, stream>>>(
        state, vleak, gleak, cm, wsNum, wsDen, (float*)d_out);
}